// Round 14
// baseline (81.262 us; speedup 1.0000x reference)
//
#include <hip/hip_runtime.h>
#include <math.h>

// SSIM loss, round 14: BARRIER-FREE per-wave pipeline.
// Evidence r8-r13: ~49us profiled floor at VALU 20-31% across occupancies
// 26-67% -> block-wide barriers convoy the waves (load together, stall
// together). r12's dataflow is nearly wave-private already (phase C reads only
// own-wave S rows). This round makes staging wave-private too:
//  - each wave stages its own 48x32 f16 panel (16-col halo duplicated between
//    neighbor waves; extra loads are L1/L2 hits), 12 coalesced float4 loads.
//  - zero __syncthreads until the final 4-word reduction; waves free-run, a
//    wave's load latency hides under 11 other resident waves' compute.
//  - panel pitch 36 f16 (72B rows: 8B-aligned -> fragment reads 2x ds_read_b64),
//    S pitch 52 (104B rows, same). LDS 54.3 KB -> 3 blocks/CU = 12 indep waves.
//  - wtab per-wave; grid restored to 6144 (r13's 1536 regressed FETCH).
// Math identical to verified r12: K=32 band MFMA h-blur, S[n][k] transpose,
// v-blur MFMA, register epilogue, 4 quantities, XCD swizzle, 2-level reduce.

typedef _Float16 f16x8 __attribute__((ext_vector_type(8)));
typedef _Float16 f16x4 __attribute__((ext_vector_type(4)));
typedef float f32x4 __attribute__((ext_vector_type(4)));
typedef _Float16 h2 __attribute__((ext_vector_type(2)));

#define PNP 36                   // f16 pitch of panel rows (32 data + 4 pad)
#define PS 52                    // f16 pitch of S rows (48 data + 4 pad)
#define PLANE (64 * PS)          // f16 per S quantity plane
#define NPIX (16 * 3 * 512 * 512)
#define NBLOCKS (48 * 16 * 8)    // 6144; % 8 == 0 -> bijective XCD swizzle

union U4 { f16x4 v; h2 p[2]; };

static __device__ __forceinline__ h2 pkrtz(float a, float b) {
    auto r = __builtin_amdgcn_cvt_pkrtz(a, b);
    union { decltype(r) f; h2 h; } x; x.f = r; return x.h;
}
static __device__ __forceinline__ f16x8 rd8(const _Float16* p) {
    const f16x4 lo = *(const f16x4*)p;
    const f16x4 hi = *(const f16x4*)(p + 4);
    f16x8 r;
    r[0] = lo[0]; r[1] = lo[1]; r[2] = lo[2]; r[3] = lo[3];
    r[4] = hi[0]; r[5] = hi[1]; r[6] = hi[2]; r[7] = hi[3];
    return r;
}

__global__ __launch_bounds__(256, 3) void ssim_main(
    const float* __restrict__ X, const float* __restrict__ Y,
    float* __restrict__ partial)
{
    static const float GWF[11] = {
        0.00102838f, 0.00759876f, 0.03600026f, 0.10936083f, 0.21300567f,
        0.26601190f, 0.21300567f, 0.10936083f, 0.03600026f, 0.00759876f,
        0.00102838f};

    __shared__ _Float16 PNL[4][2][48 * PNP];   // 27,648 B (per-wave x/y panels)
    __shared__ _Float16 S[4 * PLANE];          // 26,624 B
    __shared__ _Float16 wtab[4][16];           // per-wave band table
    __shared__ float red[4];

    const int tid = threadIdx.x;
    const int bid = blockIdx.x;

    // bijective XCD swizzle
    const int wg    = (bid & 7) * (NBLOCKS / 8) + (bid >> 3);
    const int plane = wg >> 7;           // 128 tiles per plane
    const int tt    = wg & 127;
    const int tr    = tt >> 3;           // 0..15 (row tiles, 32 rows)
    const int tc    = tt & 7;            // 0..7  (col tiles, 64 cols)

    const float* xp = X + (size_t)plane * (512 * 512);
    const float* yp = Y + (size_t)plane * (512 * 512);
    const int row0 = tr * 32 - 5;        // global row of panel row 0
    const int colT = tc * 64;            // global col of output col 0

    const int w    = tid >> 6;           // wave id = n-tile (out cols 16w..)
    const int lane = tid & 63;
    const int l15  = lane & 15;
    const int kg   = lane >> 4;

    // per-wave band table (no cross-wave dependency -> no barrier)
    if (lane < 16)
        wtab[w][lane] = (lane >= 1 && lane <= 11) ? (_Float16)GWF[lane - 1]
                                                  : (_Float16)0.0f;

    // ---- wave-private staging: 48 rows x 32 cols, 12 coalesced float4 ----
    // lane -> (lr = lane>>3 row-in-group, lc4 = lane&7 quad); 6 row groups.
    const int lr  = lane >> 3;
    const int lc4 = lane & 7;
    const int gcol = colT + 16 * w - 8 + 4 * lc4;    // per-lane constant
    const bool colOK = (gcol >= 0) && (gcol <= 508);

    const float4 f4z = make_float4(0.f, 0.f, 0.f, 0.f);
    float4 pxv[6], pyv[6];
#pragma unroll
    for (int li = 0; li < 6; ++li) {
        const int gr = row0 + 8 * li + lr;
        const bool ok = colOK && ((unsigned)gr < 512u);
        pxv[li] = ok ? *(const float4*)(xp + gr * 512 + gcol) : f4z;
        pyv[li] = ok ? *(const float4*)(yp + gr * 512 + gcol) : f4z;
    }

    _Float16* pnx = PNL[w][0];
    _Float16* pny = PNL[w][1];
#pragma unroll
    for (int li = 0; li < 6; ++li) {
        const int off = (8 * li + lr) * PNP + 4 * lc4;
        U4 tx, ty;
        tx.p[0] = pkrtz(pxv[li].x, pxv[li].y); tx.p[1] = pkrtz(pxv[li].z, pxv[li].w);
        ty.p[0] = pkrtz(pyv[li].x, pyv[li].y); ty.p[1] = pkrtz(pyv[li].z, pyv[li].w);
        *(f16x4*)(pnx + off) = tx.v;
        *(f16x4*)(pny + off) = ty.v;
    }
    // no __syncthreads: this wave reads only its own panel (lgkmcnt orders it)

    // ---- band fragments: Bh[k][n] = w[k-n-3] -> wtab[k-n-2]; Wv[m][k]=w[k-m]
    f16x8 BH, WV;
#pragma unroll
    for (int j = 0; j < 8; ++j) {
        const int kk = kg * 8 + j;
        int ib = kk - l15 - 2; ib = ib < 0 ? 0 : (ib > 15 ? 15 : ib);
        int iv = kk - l15 + 1; iv = iv < 0 ? 0 : (iv > 15 ? 15 : iv);
        BH[j] = wtab[w][ib];
        WV[j] = wtab[w][iv];
    }

    const f32x4 zero4 = {0.f, 0.f, 0.f, 0.f};

    // ---- Phase A: own-panel fragments, products, h-blur MFMA, own S rows ----
#pragma unroll
    for (int mt = 0; mt < 3; ++mt) {
        const int r = mt * 16 + l15;
        const f16x8 fx = rd8(pnx + r * PNP + 8 * kg);
        const f16x8 fy = rd8(pny + r * PNP + 8 * kg);
        const f16x8 fxy = fx * fy;
        const f16x8 fss = fx * fx + fy * fy;

        const f32x4 c0 = __builtin_amdgcn_mfma_f32_16x16x32_f16(fx,  BH, zero4, 0, 0, 0);
        const f32x4 c1 = __builtin_amdgcn_mfma_f32_16x16x32_f16(fy,  BH, zero4, 0, 0, 0);
        const f32x4 c2 = __builtin_amdgcn_mfma_f32_16x16x32_f16(fss, BH, zero4, 0, 0, 0);
        const f32x4 c3 = __builtin_amdgcn_mfma_f32_16x16x32_f16(fxy, BH, zero4, 0, 0, 0);

        // C layout: col=l15 (=n), rows=4kg..4kg+3 -> S[16w+l15][mt*16+4kg]
        _Float16* sp = S + (16 * w + l15) * PS + mt * 16 + 4 * kg;
        U4 t0, t1, t2, t3;
        t0.p[0] = pkrtz(c0[0], c0[1]); t0.p[1] = pkrtz(c0[2], c0[3]);
        t1.p[0] = pkrtz(c1[0], c1[1]); t1.p[1] = pkrtz(c1[2], c1[3]);
        t2.p[0] = pkrtz(c2[0], c2[1]); t2.p[1] = pkrtz(c2[2], c2[3]);
        t3.p[0] = pkrtz(c3[0], c3[1]); t3.p[1] = pkrtz(c3[2], c3[3]);
        *(f16x4*)(sp + 0 * PLANE) = t0.v;
        *(f16x4*)(sp + 1 * PLANE) = t1.v;
        *(f16x4*)(sp + 2 * PLANE) = t2.v;
        *(f16x4*)(sp + 3 * PLANE) = t3.v;
    }
    // no __syncthreads: phase C reads rows 16w+l15 written by this wave only

    // ---- Phase C: v-blur MFMA + SSIM epilogue ----
    const float C1 = 0.0004f, C2 = 0.0036f;
    float lsum = 0.f;
#pragma unroll
    for (int mtv = 0; mtv < 2; ++mtv) {
        const _Float16* sp = S + (16 * w + l15) * PS + 16 * mtv + kg * 8;
        const f16x8 b0 = rd8(sp + 0 * PLANE);
        const f16x8 b1 = rd8(sp + 1 * PLANE);
        const f16x8 b2 = rd8(sp + 2 * PLANE);
        const f16x8 b3 = rd8(sp + 3 * PLANE);
        const f32x4 v0 = __builtin_amdgcn_mfma_f32_16x16x32_f16(WV, b0, zero4, 0, 0, 0);
        const f32x4 v1 = __builtin_amdgcn_mfma_f32_16x16x32_f16(WV, b1, zero4, 0, 0, 0);
        const f32x4 v2 = __builtin_amdgcn_mfma_f32_16x16x32_f16(WV, b2, zero4, 0, 0, 0);
        const f32x4 v3 = __builtin_amdgcn_mfma_f32_16x16x32_f16(WV, b3, zero4, 0, 0, 0);
#pragma unroll
        for (int r2 = 0; r2 < 4; ++r2) {
            const float mux = v0[r2], muy = v1[r2];
            const float ess = v2[r2], exy = v3[r2];
            const float mux2 = mux * mux, muy2 = muy * muy, muxy = mux * muy;
            const float svar = fmaxf(ess - mux2 - muy2, 0.f);  // sxx+syy
            const float sxy = exy - muxy;
            const float num = (2.f * muxy + C1) * (2.f * sxy + C2);
            const float den = (mux2 + muy2 + C1) * (svar + C2);
            lsum += num * __builtin_amdgcn_rcpf(den);
        }
    }

    // ---- only barrier in the kernel: 4-word block reduction ----
#pragma unroll
    for (int off = 32; off > 0; off >>= 1)
        lsum += __shfl_down(lsum, off, 64);
    if (lane == 0) red[w] = lsum;
    __syncthreads();
    if (tid == 0)
        partial[bid] = red[0] + red[1] + red[2] + red[3];
}

__global__ void ssim_final(const float* __restrict__ partial,
                           float* __restrict__ out)
{
    const int tid = threadIdx.x;
    double s = 0.0;
    for (int i = tid; i < NBLOCKS; i += 1024) s += (double)partial[i];
#pragma unroll
    for (int off = 32; off > 0; off >>= 1)
        s += __shfl_down(s, off, 64);
    __shared__ double ws[16];
    if ((tid & 63) == 0) ws[tid >> 6] = s;
    __syncthreads();
    if (tid == 0) {
        double tot = 0.0;
#pragma unroll
        for (int i = 0; i < 16; ++i) tot += ws[i];
        out[0] = (float)(1.0 - tot / (double)NPIX);
    }
}

extern "C" void kernel_launch(void* const* d_in, const int* in_sizes, int n_in,
                              void* d_out, int out_size, void* d_ws, size_t ws_size,
                              hipStream_t stream)
{
    const float* x = (const float*)d_in[0];   // pred
    const float* y = (const float*)d_in[1];   // target
    float* partial = (float*)d_ws;            // NBLOCKS*4 = 24,576 B
    float* out = (float*)d_out;

    ssim_main<<<NBLOCKS, 256, 0, stream>>>(x, y, partial);
    ssim_final<<<1, 1024, 0, stream>>>(partial, out);
}

// Round 15
// 32.123 us; speedup vs baseline: 2.5297x; 2.5297x over previous
//
#include <hip/hip_runtime.h>
#include <math.h>

// SSIM loss, round 15: S LDS buffer ELIMINATED via in-wave bpermute transpose.
// h-blur C-frag (n=lane&15, rows 4kg+reg) and v-blur B-frag (n=lane&15,
// k=8kg+j) share per-lane n; the k-gather is a fixed kg-permutation:
//   B row r = 16*mtv+8kg'+2i(+1) lives in lane 16*kg_src+l15 of mt-set
//   mt = mtv + (kg'>>1), kg_src = 2*(kg'&1) + (i>>1), u32 half = i&1.
// -> per (mtv,q): 2 cndmask (mt-set select on kg>=2) + 4 ds_bpermute.
// Removes: 26.6KB S, 12 ds_write + 8 ds_read, the A->C barrier.
// LDS = raw panels only (17.0 KB); launch_bounds(256,6) -> 6 blocks/CU.
// One barrier-drain point per block (post-staging, loads needed there anyway).
// All other math identical to validated r12.

typedef _Float16 f16x8 __attribute__((ext_vector_type(8)));
typedef _Float16 f16x4 __attribute__((ext_vector_type(4)));
typedef float f32x4 __attribute__((ext_vector_type(4)));
typedef _Float16 h2 __attribute__((ext_vector_type(2)));

#define RAWP 88                  // f16 pitch of raw rows (80 data + 8 pad)
#define NPIX (16 * 3 * 512 * 512)
#define NBLOCKS (48 * 16 * 8)    // 6144; % 8 == 0 -> bijective XCD swizzle

union U4 { f16x4 v; h2 p[2]; };
union UB { unsigned u[4]; f16x8 v; };
union UP { h2 h; unsigned u; };

static __device__ __forceinline__ h2 pkrtz(float a, float b) {
    auto r = __builtin_amdgcn_cvt_pkrtz(a, b);
    union { decltype(r) f; h2 h; } x; x.f = r; return x.h;
}
static __device__ __forceinline__ unsigned pk_u32(float a, float b) {
    UP x; x.h = pkrtz(a, b); return x.u;
}

__global__ __launch_bounds__(256, 6) void ssim_main(
    const float* __restrict__ X, const float* __restrict__ Y,
    float* __restrict__ partial)
{
    static const float GWF[11] = {
        0.00102838f, 0.00759876f, 0.03600026f, 0.10936083f, 0.21300567f,
        0.26601190f, 0.21300567f, 0.10936083f, 0.03600026f, 0.00759876f,
        0.00102838f};

    __shared__ _Float16 rawx[48 * RAWP];   // 8,448 B
    __shared__ _Float16 rawy[48 * RAWP];   // 8,448 B
    __shared__ _Float16 wtab[16];
    __shared__ float red[4];

    const int tid = threadIdx.x;
    const int bid = blockIdx.x;

    if (tid < 16)
        wtab[tid] = (tid >= 1 && tid <= 11) ? (_Float16)GWF[tid - 1]
                                            : (_Float16)0.0f;

    // bijective XCD swizzle
    const int wg    = (bid & 7) * (NBLOCKS / 8) + (bid >> 3);
    const int plane = wg >> 7;           // 128 tiles per plane
    const int tt    = wg & 127;
    const int tr    = tt >> 3;           // 0..15 (row tiles, 32 rows)
    const int tc    = tt & 7;            // 0..7  (col tiles, 64 cols)

    const float* xp = X + (size_t)plane * (512 * 512);
    const float* yp = Y + (size_t)plane * (512 * 512);
    const int row0 = tr * 32 - 5;        // global row of raw row 0
    const int colT = tc * 64;            // global col of output col 0
    const int colB = colT - 8;           // global col of raw col 0

    // ---- coalesced staging: 48 rows x 20 float4-quads, f32 -> f16 ----
    for (int u = tid; u < 960; u += 256) {
        const int r  = u / 20;
        const int c4 = u - r * 20;
        const int gr = row0 + r;
        const int gc = colB + 4 * c4;
        const bool ok = ((unsigned)gr < 512u) && ((unsigned)gc <= 508u);
        float4 xv = make_float4(0.f, 0.f, 0.f, 0.f), yv = xv;
        if (ok) {
            xv = *(const float4*)(xp + gr * 512 + gc);
            yv = *(const float4*)(yp + gr * 512 + gc);
        }
        U4 tx, ty;
        tx.p[0] = pkrtz(xv.x, xv.y); tx.p[1] = pkrtz(xv.z, xv.w);
        ty.p[0] = pkrtz(yv.x, yv.y); ty.p[1] = pkrtz(yv.z, yv.w);
        *(f16x4*)(rawx + r * RAWP + 4 * c4) = tx.v;
        *(f16x4*)(rawy + r * RAWP + 4 * c4) = ty.v;
    }
    __syncthreads();                     // only block-wide barrier pre-reduce

    const int w    = tid >> 6;           // wave id = n-tile (out cols 16w..)
    const int lane = tid & 63;
    const int l15  = lane & 15;
    const int kg   = lane >> 4;

    // band fragments: Bh[k][n] = w[k-n-3] -> wtab[k-n-2]; Wv[m][k] = w[k-m]
    f16x8 BH, WV;
#pragma unroll
    for (int j = 0; j < 8; ++j) {
        const int kk = kg * 8 + j;
        int ib = kk - l15 - 2; ib = ib < 0 ? 0 : (ib > 15 ? 15 : ib);
        int iv = kk - l15 + 1; iv = iv < 0 ? 0 : (iv > 15 ? 15 : iv);
        BH[j] = wtab[ib];
        WV[j] = wtab[iv];
    }

    const f32x4 zero4 = {0.f, 0.f, 0.f, 0.f};
    const int rawc = 16 * w + 8 * kg;    // phase-A raw col (8 f16, 16B aligned)

    // ---- Phase A: fragments, products, h-blur MFMA -> packed C in regs ----
    // pq[q][mt][half]: half0 = rows(4kg,4kg+1), half1 = rows(4kg+2,4kg+3)
    unsigned pq[4][3][2];
#pragma unroll
    for (int mt = 0; mt < 3; ++mt) {
        const int r = mt * 16 + l15;
        const f16x8 fx = *(const f16x8*)(rawx + r * RAWP + rawc);
        const f16x8 fy = *(const f16x8*)(rawy + r * RAWP + rawc);
        const f16x8 fxy = fx * fy;
        const f16x8 fss = fx * fx + fy * fy;

        const f32x4 c0 = __builtin_amdgcn_mfma_f32_16x16x32_f16(fx,  BH, zero4, 0, 0, 0);
        const f32x4 c1 = __builtin_amdgcn_mfma_f32_16x16x32_f16(fy,  BH, zero4, 0, 0, 0);
        const f32x4 c2 = __builtin_amdgcn_mfma_f32_16x16x32_f16(fss, BH, zero4, 0, 0, 0);
        const f32x4 c3 = __builtin_amdgcn_mfma_f32_16x16x32_f16(fxy, BH, zero4, 0, 0, 0);

        pq[0][mt][0] = pk_u32(c0[0], c0[1]); pq[0][mt][1] = pk_u32(c0[2], c0[3]);
        pq[1][mt][0] = pk_u32(c1[0], c1[1]); pq[1][mt][1] = pk_u32(c1[2], c1[3]);
        pq[2][mt][0] = pk_u32(c2[0], c2[1]); pq[2][mt][1] = pk_u32(c2[2], c2[3]);
        pq[3][mt][0] = pk_u32(c3[0], c3[1]); pq[3][mt][1] = pk_u32(c3[2], c3[3]);
    }

    // ---- Phase C: bpermute-built B-frags, v-blur MFMA, epilogue ----
    const int addrA = ((2 * (kg & 1)) * 16 + l15) * 4;   // byte lane addr
    const int addrB = addrA + 64;                        // +16 lanes
    const bool hi = (kg >= 2);                           // mt-set = mtv+1

    const float C1 = 0.0004f, C2 = 0.0036f;
    float lsum = 0.f;
#pragma unroll
    for (int mtv = 0; mtv < 2; ++mtv) {
        f32x4 v[4];
#pragma unroll
        for (int q = 0; q < 4; ++q) {
            const unsigned s0 = hi ? pq[q][mtv + 1][0] : pq[q][mtv][0];
            const unsigned s1 = hi ? pq[q][mtv + 1][1] : pq[q][mtv][1];
            UB b;
            b.u[0] = (unsigned)__builtin_amdgcn_ds_bpermute(addrA, (int)s0);
            b.u[1] = (unsigned)__builtin_amdgcn_ds_bpermute(addrA, (int)s1);
            b.u[2] = (unsigned)__builtin_amdgcn_ds_bpermute(addrB, (int)s0);
            b.u[3] = (unsigned)__builtin_amdgcn_ds_bpermute(addrB, (int)s1);
            v[q] = __builtin_amdgcn_mfma_f32_16x16x32_f16(WV, b.v, zero4, 0, 0, 0);
        }
#pragma unroll
        for (int r2 = 0; r2 < 4; ++r2) {
            const float mux = v[0][r2], muy = v[1][r2];
            const float ess = v[2][r2], exy = v[3][r2];
            const float mux2 = mux * mux, muy2 = muy * muy, muxy = mux * muy;
            const float svar = fmaxf(ess - mux2 - muy2, 0.f);  // sxx+syy
            const float sxy = exy - muxy;
            const float num = (2.f * muxy + C1) * (2.f * sxy + C2);
            const float den = (mux2 + muy2 + C1) * (svar + C2);
            lsum += num * __builtin_amdgcn_rcpf(den);
        }
    }

    // ---- block reduction ----
#pragma unroll
    for (int off = 32; off > 0; off >>= 1)
        lsum += __shfl_down(lsum, off, 64);
    if (lane == 0) red[w] = lsum;
    __syncthreads();
    if (tid == 0)
        partial[bid] = red[0] + red[1] + red[2] + red[3];
}

__global__ void ssim_final(const float* __restrict__ partial,
                           float* __restrict__ out)
{
    const int tid = threadIdx.x;
    double s = 0.0;
    for (int i = tid; i < NBLOCKS; i += 1024) s += (double)partial[i];
#pragma unroll
    for (int off = 32; off > 0; off >>= 1)
        s += __shfl_down(s, off, 64);
    __shared__ double ws[16];
    if ((tid & 63) == 0) ws[tid >> 6] = s;
    __syncthreads();
    if (tid == 0) {
        double tot = 0.0;
#pragma unroll
        for (int i = 0; i < 16; ++i) tot += ws[i];
        out[0] = (float)(1.0 - tot / (double)NPIX);
    }
}

extern "C" void kernel_launch(void* const* d_in, const int* in_sizes, int n_in,
                              void* d_out, int out_size, void* d_ws, size_t ws_size,
                              hipStream_t stream)
{
    const float* x = (const float*)d_in[0];   // pred
    const float* y = (const float*)d_in[1];   // target
    float* partial = (float*)d_ws;            // NBLOCKS*4 = 24,576 B
    float* out = (float*)d_out;

    ssim_main<<<NBLOCKS, 256, 0, stream>>>(x, y, partial);
    ssim_final<<<1, 1024, 0, stream>>>(partial, out);
}